// Round 5
// baseline (78.508 us; speedup 1.0000x reference)
//
#include <hip/hip_runtime.h>

// DAG reachability closure from node 0. N=8192 nodes, left/right child in
// [-1, N). Reference = N relaxation steps == transitive closure from node 0.
//
// Calibration (R0-R4): timed region = kernel + ~52 us fixed harness cost.
// All sync-structure variants stall at ~20-22 us kernel because pass count
// (~BFS depth ~30) x per-pass latency (~0.7 us: 16-wave barrier skew +
// dependent LDS read) dominates. This version cuts PASS COUNT 3x:
//
//   3-HOP EDGE TABLE: precompute each node's 8 great-grandchildren
//   (u16, sentinel 0xFFFF) = 16 B/node = 128 KB LDS, built in-place over
//   the 64 KB 1-hop staging area (register-gather -> barrier -> overwrite).
//   Seed reach with depths {0,1,2} (node 0 + children + grandchildren);
//   BFS on the 3-hop graph then needs ceil(depth/3) ~ 11 passes, each
//   expansion one ds_read_b128 (all 8 children) + 8 fire-and-forget
//   atomicOr. Rotating-flag single-barrier pass structure kept from R4;
//   INNER=2 chaotic sub-iterations as cheap extra-hop insurance.
// Output: bool mask -> INT32 0/1 (harness reads bool output as int32).

#define NMAX   8192
#define BLK    1024
#define NWORDS (NMAX / 32)
#define SENT   0xFFFFu

__global__ __launch_bounds__(BLK) void dag_reach_kernel(
    const int* __restrict__ left,
    const int* __restrict__ right,
    int* __restrict__ out,
    int n)
{
    __shared__ __align__(16) unsigned short A3[NMAX * 8]; // 128 KB: 3-hop u16x8
    __shared__ unsigned int reach[NWORDS];                // 1 KB bitmask
    __shared__ int s_flag[3];                             // rotating flags

    int2* A2 = reinterpret_cast<int2*>(A3);               // 1-hop staging (first 64 KB)

    const int tid  = threadIdx.x;
    const int base = tid * 8;                             // my 8 nodes

    // ---- Stage 1-hop edges: int4 global loads, packed int2 LDS writes ----
    if (base + 7 < n) {
        int4 l0 = *reinterpret_cast<const int4*>(left  + base);
        int4 l1 = *reinterpret_cast<const int4*>(left  + base + 4);
        int4 r0 = *reinterpret_cast<const int4*>(right + base);
        int4 r1 = *reinterpret_cast<const int4*>(right + base + 4);
        A2[base + 0] = make_int2(l0.x, r0.x);
        A2[base + 1] = make_int2(l0.y, r0.y);
        A2[base + 2] = make_int2(l0.z, r0.z);
        A2[base + 3] = make_int2(l0.w, r0.w);
        A2[base + 4] = make_int2(l1.x, r1.x);
        A2[base + 5] = make_int2(l1.y, r1.y);
        A2[base + 6] = make_int2(l1.z, r1.z);
        A2[base + 7] = make_int2(l1.w, r1.w);
    } else {
        for (int k = base; k < n; ++k) A2[k] = make_int2(left[k], right[k]);
    }
    if (tid < NWORDS) reach[tid] = 0u;
    if (tid < 3)      s_flag[tid] = 0;
    __syncthreads();

    // ---- Gather 3-hop children into registers (reads only) ----
    int4 h[8];                                            // 8 nodes x (8 u16 packed)
    #pragma unroll
    for (int j = 0; j < 8; ++j) {
        const int v = base + j;
        const int SS = (int)(SENT | (SENT << 16));
        int4 w = make_int4(SS, SS, SS, SS);
        if (v < n) {
            int2 c  = A2[v];
            int2 g0 = (c.x  >= 0) ? A2[c.x]  : make_int2(-1, -1);
            int2 g1 = (c.y  >= 0) ? A2[c.y]  : make_int2(-1, -1);
            int2 q0 = (g0.x >= 0) ? A2[g0.x] : make_int2(-1, -1);
            int2 q1 = (g0.y >= 0) ? A2[g0.y] : make_int2(-1, -1);
            int2 q2 = (g1.x >= 0) ? A2[g1.x] : make_int2(-1, -1);
            int2 q3 = (g1.y >= 0) ? A2[g1.y] : make_int2(-1, -1);
            #define PK(a, b) (int)(((a) >= 0 ? (unsigned)(a) : SENT) | \
                                   (((b) >= 0 ? (unsigned)(b) : SENT) << 16))
            w = make_int4(PK(q0.x, q0.y), PK(q1.x, q1.y),
                          PK(q2.x, q2.y), PK(q3.x, q3.y));
            #undef PK
            if (v == 0) {   // seed depths {0,1,2}: node 0, children, grandchildren
                atomicOr(&reach[0], 1u);
                if (c.x  >= 0) atomicOr(&reach[c.x  >> 5], 1u << (c.x  & 31));
                if (c.y  >= 0) atomicOr(&reach[c.y  >> 5], 1u << (c.y  & 31));
                if (g0.x >= 0) atomicOr(&reach[g0.x >> 5], 1u << (g0.x & 31));
                if (g0.y >= 0) atomicOr(&reach[g0.y >> 5], 1u << (g0.y & 31));
                if (g1.x >= 0) atomicOr(&reach[g1.x >> 5], 1u << (g1.x & 31));
                if (g1.y >= 0) atomicOr(&reach[g1.y >> 5], 1u << (g1.y & 31));
            }
        }
        h[j] = w;
    }
    __syncthreads();                   // all gathers done before overwrite

    // ---- Scatter 3-hop table in place (one ds_write_b128 per node) ----
    #pragma unroll
    for (int j = 0; j < 8; ++j) {
        *reinterpret_cast<int4*>(&A3[(base + j) * 8]) = h[j];
    }
    __syncthreads();

    // ---- Chaotic BFS on the 3-hop graph, single barrier per pass ----
    const int word_idx = tid >> 2;     // my reach word
    const int shift    = (tid & 3) * 8;
    unsigned int expanded = 0u;
    volatile unsigned int* vreach = reach;

    #define EXPAND8(W) do {                                                   \
        unsigned _a;                                                          \
        _a = (unsigned)(W).x & 0xFFFFu; if (_a != SENT) atomicOr(&reach[_a >> 5], 1u << (_a & 31)); \
        _a = (unsigned)(W).x >> 16;     if (_a != SENT) atomicOr(&reach[_a >> 5], 1u << (_a & 31)); \
        _a = (unsigned)(W).y & 0xFFFFu; if (_a != SENT) atomicOr(&reach[_a >> 5], 1u << (_a & 31)); \
        _a = (unsigned)(W).y >> 16;     if (_a != SENT) atomicOr(&reach[_a >> 5], 1u << (_a & 31)); \
        _a = (unsigned)(W).z & 0xFFFFu; if (_a != SENT) atomicOr(&reach[_a >> 5], 1u << (_a & 31)); \
        _a = (unsigned)(W).z >> 16;     if (_a != SENT) atomicOr(&reach[_a >> 5], 1u << (_a & 31)); \
        _a = (unsigned)(W).w & 0xFFFFu; if (_a != SENT) atomicOr(&reach[_a >> 5], 1u << (_a & 31)); \
        _a = (unsigned)(W).w >> 16;     if (_a != SENT) atomicOr(&reach[_a >> 5], 1u << (_a & 31)); \
    } while (0)

    int p3 = 0;
    while (true) {
        const int pn3 = (p3 == 2) ? 0 : p3 + 1;
        int ch = 0;

        #pragma unroll
        for (int it = 0; it < 2; ++it) {
            unsigned int pend = ((vreach[word_idx] >> shift) & 0xFFu) & ~expanded;
            if (pend) {
                ch = 1;
                expanded |= pend;
                while (pend) {
                    // peel up to 2 pending nodes -> 2 independent ds_read_b128
                    int b0 = __ffs(pend) - 1; pend &= pend - 1;
                    int b1 = -1;
                    if (pend) { b1 = __ffs(pend) - 1; pend &= pend - 1; }
                    int4 w0 = *reinterpret_cast<const int4*>(&A3[(base + b0) * 8]);
                    int4 w1 = *reinterpret_cast<const int4*>(
                                  &A3[(base + (b1 < 0 ? b0 : b1)) * 8]);
                    EXPAND8(w0);
                    if (b1 >= 0) EXPAND8(w1);
                }
            }
        }

        // Wave-aggregated flag update + next-slot reset (benign races).
        if ((tid & 63) == 0) s_flag[pn3] = 0;
        if (__any(ch) && (tid & 63) == 0) s_flag[p3] = 1;
        __syncthreads();               // the ONLY barrier per pass
        if (!s_flag[p3]) break;        // uniform: fixpoint reached
        p3 = pn3;
    }
    #undef EXPAND8

    // ---- Write bool mask as int32 0/1 (16 B per lane, coalesced) ----
    for (int i = 4 * tid; i < n; i += 4 * BLK) {
        const unsigned w = reach[i >> 5];
        const int b = i & 31;
        *reinterpret_cast<int4*>(out + i) =
            make_int4((int)((w >> (b + 0)) & 1u),
                      (int)((w >> (b + 1)) & 1u),
                      (int)((w >> (b + 2)) & 1u),
                      (int)((w >> (b + 3)) & 1u));
    }
}

extern "C" void kernel_launch(void* const* d_in, const int* in_sizes, int n_in,
                              void* d_out, int out_size, void* d_ws, size_t ws_size,
                              hipStream_t stream)
{
    // inputs: 0 = thresholds (f32, UNUSED by reference), 1 = left (i32), 2 = right (i32)
    const int* left  = (const int*)d_in[1];
    const int* right = (const int*)d_in[2];
    int* out = (int*)d_out;
    const int n = in_sizes[1];

    dag_reach_kernel<<<1, BLK, 0, stream>>>(left, right, out, n);
}